// Round 1
// 289.016 us; speedup vs baseline: 1.0091x; 1.0091x over previous
//
#include <hip/hip_runtime.h>
#include <math.h>

// Problem constants (from setup_inputs): B=8, D=512, Dh=64, T=8192, chunksize=16
#define BB 8
#define DD 512
#define DH 64
#define TT 8192
#define CS 16
#define CC 512   // T / chunksize

__device__ __forceinline__ float sigf(float v) {
    return 1.0f / (1.0f + __expf(-v));
}

// ---------------------------------------------------------------------------
// K1: pooled[b,d,c] = (1/(16*(c+1))) * sum_{t<16(c+1)} x[b,d,t]
// One block per (b,d) row. 256 threads.  (verified in previous session)
// ---------------------------------------------------------------------------
__global__ __launch_bounds__(256) void k_pool(
        const float* __restrict__ x, float* __restrict__ pooled) {
    const int row = blockIdx.x;               // b*512 + d
    const int t = threadIdx.x;
    const float4* xr = (const float4*)(x + (size_t)row * TT);

    __shared__ float psum[2048];              // per-float4 partial sums
    __shared__ float wtot[4];

    #pragma unroll
    for (int k = 0; k < 8; k++) {
        float4 v = xr[t + k * 256];
        psum[t + k * 256] = (v.x + v.y) + (v.z + v.w);
    }
    __syncthreads();

    // chunk c = 16 floats = 4 float4 partials; thread t owns chunks 2t, 2t+1
    const float4* ps4 = (const float4*)psum;
    float4 q0 = ps4[2 * t];
    float4 q1 = ps4[2 * t + 1];
    float c0 = (q0.x + q0.y) + (q0.z + q0.w);
    float c1 = (q1.x + q1.y) + (q1.z + q1.w);

    // inclusive scan of pair-sums across 256 threads
    float ps = c0 + c1;
    float v = ps;
    int lane = t & 63;
    #pragma unroll
    for (int off = 1; off < 64; off <<= 1) {
        float n = __shfl_up(v, off, 64);
        if (lane >= off) v += n;
    }
    int wid = t >> 6;
    if (lane == 63) wtot[wid] = v;
    __syncthreads();
    float wpre = 0.0f;
    for (int w = 0; w < wid; w++) wpre += wtot[w];
    float incl = v + wpre;          // sum of chunks 0..2t+1
    float excl = incl - ps;         // sum of chunks 0..2t-1
    float s0 = excl + c0;           // inclusive through chunk 2t
    float s1 = s0 + c1;             // inclusive through chunk 2t+1
    int c = 2 * t;
    float2 outv;
    outv.x = s0 / (float)(CS * (c + 1));
    outv.y = s1 / (float)(CS * (c + 2));
    ((float2*)(pooled + (size_t)row * CC))[t] = outv;
}

// ---------------------------------------------------------------------------
// K2: fused  h = relu(w1 @ pooled + b1); g = sigmoid(w2 @ h + b2);
//            out[b,d,t] = g[b,d,t/16] * x[b,d,t]
// Block = (ctile of 4 chunks, b). 256 threads.
// Reads w1 (64x512) row-contiguous per o; w2 (512x64) row-contiguous per o2 —
// no weight transpose kernel needed (both 128 KB, L2-resident).
// ---------------------------------------------------------------------------
#define PSTR 516   // padded LDS stride (516 % 32 == 4 -> conflict-free, 16B-aligned)

__global__ __launch_bounds__(256) void k_fused(
        const float* __restrict__ x,
        const float* __restrict__ pooled,
        const float* __restrict__ w1, const float* __restrict__ b1,
        const float* __restrict__ w2, const float* __restrict__ b2,
        float* __restrict__ out) {
    const int b = blockIdx.y;
    const int c0 = blockIdx.x * 4;            // first chunk of this tile
    const int t = threadIdx.x;

    __shared__ float p[4 * PSTR];   // p[c][d] = p[c*PSTR + d]
    __shared__ float hs[DH * 4];    // hs[4*o + c]
    __shared__ float gs[DD * 4];    // gs[4*o2 + c]  (the gate values)

    // stage pooled[b, :, c0..c0+3] transposed into LDS
    {
        const float4* src = (const float4*)(pooled + (size_t)b * DD * CC + c0);
        float4 v0 = src[(size_t)t * (CC / 4)];
        float4 v1 = src[((size_t)t + 256) * (CC / 4)];
        p[0 * PSTR + t] = v0.x; p[1 * PSTR + t] = v0.y;
        p[2 * PSTR + t] = v0.z; p[3 * PSTR + t] = v0.w;
        p[0 * PSTR + t + 256] = v1.x; p[1 * PSTR + t + 256] = v1.y;
        p[2 * PSTR + t + 256] = v1.z; p[3 * PSTR + t + 256] = v1.w;
    }
    __syncthreads();

    // GEMM1: thread t -> o = t>>2, c = t&3 ; K = 512 over d.
    // w1 row o is 2 KB contiguous -> float4 loads (L2 broadcast across the
    // 4 lanes sharing o).
    const int o = t >> 2, c = t & 3;
    const float4* w1r = (const float4*)(w1 + (size_t)o * DD);
    const float4* pc = (const float4*)(p + c * PSTR);
    float a0 = 0.f, a1 = 0.f, a2 = 0.f, a3 = 0.f;
    #pragma unroll 4
    for (int d4 = 0; d4 < 128; d4++) {
        float4 wv = w1r[d4];
        float4 pv = pc[d4];
        a0 = fmaf(wv.x, pv.x, a0);
        a1 = fmaf(wv.y, pv.y, a1);
        a2 = fmaf(wv.z, pv.z, a2);
        a3 = fmaf(wv.w, pv.w, a3);
    }
    float hv = ((a0 + a1) + (a2 + a3)) + b1[o];
    hs[t] = fmaxf(hv, 0.0f);        // hs[4o + c] since t = 4o + c
    __syncthreads();

    // GEMM2: thread t -> o2 = {t, t+256}, 4 c's each; K = 64 over o.
    // w2 row o2 is 256 B contiguous -> 16 float4 loads per o2.
    {
        const float4* h4 = (const float4*)hs;
        const float4* w2a = (const float4*)(w2 + (size_t)t * DH);
        const float4* w2b = (const float4*)(w2 + ((size_t)t + 256) * DH);
        float gA0 = 0, gA1 = 0, gA2 = 0, gA3 = 0;
        float gB0 = 0, gB1 = 0, gB2 = 0, gB3 = 0;
        #pragma unroll 4
        for (int q = 0; q < 16; q++) {
            float4 wa = w2a[q];
            float4 wb = w2b[q];
            float4 hA = h4[4 * q + 0];   // h[4q+0][c=0..3]
            float4 hB = h4[4 * q + 1];
            float4 hC = h4[4 * q + 2];
            float4 hD = h4[4 * q + 3];
            gA0 = fmaf(wa.x, hA.x, gA0); gA0 = fmaf(wa.y, hB.x, gA0);
            gA0 = fmaf(wa.z, hC.x, gA0); gA0 = fmaf(wa.w, hD.x, gA0);
            gA1 = fmaf(wa.x, hA.y, gA1); gA1 = fmaf(wa.y, hB.y, gA1);
            gA1 = fmaf(wa.z, hC.y, gA1); gA1 = fmaf(wa.w, hD.y, gA1);
            gA2 = fmaf(wa.x, hA.z, gA2); gA2 = fmaf(wa.y, hB.z, gA2);
            gA2 = fmaf(wa.z, hC.z, gA2); gA2 = fmaf(wa.w, hD.z, gA2);
            gA3 = fmaf(wa.x, hA.w, gA3); gA3 = fmaf(wa.y, hB.w, gA3);
            gA3 = fmaf(wa.z, hC.w, gA3); gA3 = fmaf(wa.w, hD.w, gA3);
            gB0 = fmaf(wb.x, hA.x, gB0); gB0 = fmaf(wb.y, hB.x, gB0);
            gB0 = fmaf(wb.z, hC.x, gB0); gB0 = fmaf(wb.w, hD.x, gB0);
            gB1 = fmaf(wb.x, hA.y, gB1); gB1 = fmaf(wb.y, hB.y, gB1);
            gB1 = fmaf(wb.z, hC.y, gB1); gB1 = fmaf(wb.w, hD.y, gB1);
            gB2 = fmaf(wb.x, hA.z, gB2); gB2 = fmaf(wb.y, hB.z, gB2);
            gB2 = fmaf(wb.z, hC.z, gB2); gB2 = fmaf(wb.w, hD.z, gB2);
            gB3 = fmaf(wb.x, hA.w, gB3); gB3 = fmaf(wb.y, hB.w, gB3);
            gB3 = fmaf(wb.z, hC.w, gB3); gB3 = fmaf(wb.w, hD.w, gB3);
        }
        float bbA = b2[t], bbB = b2[t + 256];
        float4 rA, rB;
        rA.x = sigf(gA0 + bbA); rA.y = sigf(gA1 + bbA);
        rA.z = sigf(gA2 + bbA); rA.w = sigf(gA3 + bbA);
        rB.x = sigf(gB0 + bbB); rB.y = sigf(gB1 + bbB);
        rB.z = sigf(gB2 + bbB); rB.w = sigf(gB3 + bbB);
        float4* gs4 = (float4*)gs;
        gs4[t] = rA;           // gs[4*o2 + c] for o2 = t
        gs4[t + 256] = rB;     // o2 = t + 256
    }
    __syncthreads();

    // Gate phase: this block owns x[b, :, c0*16 .. c0*16+63]
    // = 512 rows x 16 float4.  8192 float4 -> 32 per thread, unroll 8.
    // Per wave instruction: 4 rows x 256 B contiguous segments (coalesced).
    {
        const size_t base = (size_t)b * DD * (TT / 4) + (size_t)c0 * 4;
        const float4* x4 = (const float4*)x + base;
        float4* o4 = (float4*)out + base;
        #pragma unroll 8
        for (int k = 0; k < 32; k++) {
            int idx = k * 256 + t;
            int d = idx >> 4;            // row within (b, :)
            int t4 = idx & 15;           // float4 within the 64-float span
            size_t a = (size_t)d * (TT / 4) + t4;
            float4 xv = x4[a];
            float gv = gs[d * 4 + (t4 >> 2)];
            float4 r;
            r.x = xv.x * gv; r.y = xv.y * gv;
            r.z = xv.z * gv; r.w = xv.w * gv;
            o4[a] = r;
        }
    }
}

// ---------------------------------------------------------------------------
extern "C" void kernel_launch(void* const* d_in, const int* in_sizes, int n_in,
                              void* d_out, int out_size, void* d_ws, size_t ws_size,
                              hipStream_t stream) {
    const float* x  = (const float*)d_in[0];
    const float* w1 = (const float*)d_in[1];
    const float* b1 = (const float*)d_in[2];
    const float* w2 = (const float*)d_in[3];
    const float* b2 = (const float*)d_in[4];
    float* out = (float*)d_out;

    // workspace layout (bytes): pooled 8MB
    float* pooled = (float*)d_ws;

    k_pool<<<dim3(BB * DD), dim3(256), 0, stream>>>(x, pooled);
    k_fused<<<dim3(CC / 4, BB), dim3(256), 0, stream>>>(
        x, pooled, w1, b1, w2, b2, out);
}